// Round 5
// baseline (1187.819 us; speedup 1.0000x reference)
//
#include <hip/hip_runtime.h>

typedef unsigned short u16;
typedef unsigned int   u32;

// B_=512, N=392, C=128, nH=4, hd=32, nW=128
#define NTOK   392
#define NN2    153664      // 392*392
#define LOG2E  1.44269504088896340736f
#define QSCL   (0.17677669529663687f * 1.44269504088896340736f)   // QSCALE * LOG2E
#define BTK    416         // bias padded key dim (and q dim)
#define BTH    (416L*416L) // bias per-head plane elems

typedef __attribute__((ext_vector_type(8))) __bf16 bf16x8;
typedef __attribute__((ext_vector_type(4))) float  f32x4;
#define MFMA16(a,b,c) __builtin_amdgcn_mfma_f32_16x16x32_bf16((a),(b),(c),0,0,0)

__device__ __forceinline__ float bf2f(u16 u){
    union { u32 i; float f; } v; v.i = ((u32)u) << 16; return v.f;
}
__device__ __forceinline__ u16 f2bf(float x){
    union { float f; u32 i; } v; v.f = x;
    u32 r = (v.i + 0x7FFFu + ((v.i >> 16) & 1u)) >> 16;
    return (u16)r;
}
__device__ __forceinline__ u16 bfbits(float x){
    union { __bf16 b; u16 u; } v; v.b = (__bf16)x; return v.u;
}
__device__ __forceinline__ u32 pk2(float a, float b){
    return (u32)bfbits(a) | ((u32)bfbits(b) << 16);
}
__device__ __forceinline__ u16 f16b(float x){
    union { _Float16 h; u16 u; } t; t.h = (_Float16)x; return t.u;
}
// 4 fp16 (as uint2) -> f32x4
__device__ __forceinline__ f32x4 h4tof(uint2 u){
    union { u32 w; _Float16 h[2]; } a, b;
    a.w = u.x; b.w = u.y;
    f32x4 r = { (float)a.h[0], (float)a.h[1], (float)b.h[0], (float)b.h[1] };
    return r;
}
// adaptive loads/stores: isb=1 -> packed bf16 storage, isb=0 -> fp32 storage
__device__ __forceinline__ float ldf(const void* p, int isb, long i){
    if (isb) return bf2f(((const u16*)p)[i]);
    else     return ((const float*)p)[i];
}
__device__ __forceinline__ void stf(void* p, int isb, long i, float v){
    if (isb) ((u16*)p)[i] = f2bf(v);
    else     ((float*)p)[i] = v;
}

// load 8 consecutive values from global, split into hi/lo bf16 fragments.
__device__ __forceinline__ void ld8s(const void* p, int isb, long i0,
                                     bf16x8* h, bf16x8* l){
    union { u16 u[8]; bf16x8 v; } H, L;
    if (isb){
        const uint2* q = (const uint2*)((const u16*)p + i0);
        uint2 a = q[0], b = q[1];
        H.u[0]=(u16)a.x; H.u[1]=(u16)(a.x>>16); H.u[2]=(u16)a.y; H.u[3]=(u16)(a.y>>16);
        H.u[4]=(u16)b.x; H.u[5]=(u16)(b.x>>16); H.u[6]=(u16)b.y; H.u[7]=(u16)(b.y>>16);
        #pragma unroll
        for (int j = 0; j < 8; ++j) L.u[j] = 0;
    } else {
        const float4* q = (const float4*)((const float*)p + i0);
        float4 a = q[0], b = q[1];
        float f[8] = {a.x,a.y,a.z,a.w,b.x,b.y,b.z,b.w};
        #pragma unroll
        for (int j = 0; j < 8; ++j){
            u16 hh = f2bf(f[j]);
            H.u[j] = hh;
            L.u[j] = f2bf(f[j] - bf2f(hh));
        }
    }
    *h = H.v; *l = L.v;
}

// ---------- kernel A: storage-dtype detection on x ----------
__device__ __forceinline__ int plaus(u16 w){
    int e = (w >> 7) & 0xFF;
    return (w == 0) || (e >= 96 && e <= 145);
}
__global__ __launch_bounds__(256) void prep_kernel(
        const u16* __restrict__ x, int* __restrict__ flags){
    __shared__ int cnt[2];
    int tid = threadIdx.x;
    if (tid < 2) cnt[tid] = 0;
    __syncthreads();
    int p = plaus(x[tid]) + plaus(x[tid + 256]);
    if (p) atomicAdd(&cnt[0], p);
    int ez = ((tid & 1) == 0 && x[tid] == 0) + (((tid + 256) & 1) == 0 && x[tid + 256] == 0);
    if (ez) atomicAdd(&cnt[1], ez);
    __syncthreads();
    if (tid == 0){
        flags[0] = (cnt[1] < 64 && cnt[0] >= 436) ? 1 : 0;
        flags[4] = 0;
    }
}

// ---------- kernel B: mask nonzero scan ----------
__global__ __launch_bounds__(256) void mask_scan_kernel(
        const u32* __restrict__ m, int nhalf, const int* __restrict__ flagsRO,
        int* __restrict__ flags){
    long nw = flagsRO[0] ? nhalf : 2L * nhalf;
    long i0 = (long)blockIdx.x * 256 + threadIdx.x;
    u32 acc = 0;
    for (long i = i0; i < nw; i += (long)gridDim.x * 256) acc |= m[i];
    if (acc) atomicOr(&flags[4], 1);
}

// ---------- kernel C: bias biasH[h][q(416)][key(416)] = fp16(bias*LOG2E) ----------
// pad: key>=392 -> -25000 (exp2 -> 0, finite), q>=392 -> 0 (harmless, stores gated)
__global__ __launch_bounds__(256) void bias_expand_kernel(
        const int* __restrict__ rel_index, const void* btabP,
        const int* __restrict__ flags, u16* __restrict__ biasH){
    long idx = (long)blockIdx.x * 256 + threadIdx.x;
    if (idx >= BTH) return;
    int q   = (int)(idx / BTK);
    int key = (int)(idx - (long)q * BTK);
    int isb = flags[0];
    float v0, v1, v2, v3;
    if (key >= NTOK){ v0 = v1 = v2 = v3 = -25000.f; }
    else if (q >= NTOK){ v0 = v1 = v2 = v3 = 0.f; }
    else {
        int t = rel_index[(long)q * NTOK + key];
        v0 = ldf(btabP, isb, (long)t * 4 + 0) * LOG2E;
        v1 = ldf(btabP, isb, (long)t * 4 + 1) * LOG2E;
        v2 = ldf(btabP, isb, (long)t * 4 + 2) * LOG2E;
        v3 = ldf(btabP, isb, (long)t * 4 + 3) * LOG2E;
    }
    biasH[0 * BTH + idx] = f16b(v0);
    biasH[1 * BTH + idx] = f16b(v1);
    biasH[2 * BTH + idx] = f16b(v2);
    biasH[3 * BTH + idx] = f16b(v3);
}

// ---------- kernel D: fused MFMA window attention ----------
// block = (head h FAST, window b_), 832 threads = 13 waves, LDS 73 KB -> 2 blocks/CU.
// Phase 1: 13 chunks of 32 tokens. Per chunk: stage x, 12 (mt,nt) jobs on waves 0..11
//   (1 job each; wave 12 stages only). Q-tiles go through a tiny double-buffered smQ
//   (cross-wave transpose) and are captured into registers qS0/qS1 at the next
//   chunk's top; K -> Kh[tok][32], V -> VT[d][416].
// Phase 2: 26 tasks of 16 q-rows = 13 waves x 2 passes (perfect balance, no barriers).
//   Swapped QK^T (A=K,B=Q), fp16 bias as MFMA C-operand (ring-1 prefetch), exp2,
//   packed-b64 P bounce per wave, PV per 32-key pair from VT.
__global__ __launch_bounds__(832, 7) void attn_mfma_kernel(
        const void* xP, const void* qwP, const void* maskP,
        const u16* __restrict__ biasH, const int* __restrict__ flags,
        void* outP){
    __shared__ __align__(16) u16 Kh[416 * 32];        // 26624 B  K bf16 [key][d]
    __shared__ __align__(16) u16 VT[32 * 416];        // 26624 B  V bf16 [d][key]
    __shared__ __align__(16) u16 uni[2 * 32 * 136];   // 17408 B  xs_hi/lo; ph2: P bounce
    __shared__ __align__(16) u16 smQ[2 * 32 * 32];    //  4096 B  Q transpose dbuf
    // total 74752 B -> 2 blocks/CU, 26 waves/CU

    u16* xs_hi = uni;
    u16* xs_lo = uni + 32 * 136;

    const int tid  = threadIdx.x;
    const int lane = tid & 63;
    const int wv   = tid >> 6;          // 0..12
    const int c    = lane & 15;
    const int g    = lane >> 4;
    const int h    = blockIdx.x;        // head FAST: 4 heads of a window adjacent
    const int b_   = blockIdx.y;
    const int wdx  = b_ & 127;
    const int isb  = flags[0], fm = flags[4];
    const long xbase = (long)b_ * NTOK * 128;

    // ---------- phase 1: QKV projection via MFMA ----------
    // wave wv<12: fixed job (ntw = wv>>1 of {Q0,Q1,K0,K1,V0,V1}, mtw = wv&1)
    const int ntw = wv >> 1;
    const int mtw = wv & 1;
    bf16x8 WHr[4], WLr[4];
    if (wv < 12){
        int nn = ntw * 16 + c;          // 0..95
        int wrow = (nn < 32) ? (h * 32 + nn)
                 : (nn < 64) ? (128 + h * 32 + (nn - 32))
                 :             (256 + h * 32 + (nn - 64));
        #pragma unroll
        for (int ks = 0; ks < 4; ++ks)
            ld8s(qwP, isb, (long)wrow * 128 + ks * 32 + 8 * g, &WHr[ks], &WLr[ks]);
    }

    bf16x8 qS0 = {}, qS1 = {};          // captured Q fragments (tasks wv, wv+13)

    for (int ch = 0; ch < 13; ++ch){
        const int tok0 = ch * 32;
        __syncthreads();                // prev chunk xs reads + smQ[(ch-1)&1] writes done
        if (ch > 0){
            const int cp = ch - 1;
            const u16* sq = smQ + (cp & 1) * 1024;
            const int t0 = 2 * cp, t1 = t0 + 1;
            if (wv == t0 % 13){
                bf16x8 v = *(const bf16x8*)&sq[c * 32 + 8 * g];
                if (t0 < 13) qS0 = v; else qS1 = v;
            }
            if (wv == t1 % 13){
                bf16x8 v = *(const bf16x8*)&sq[(16 + c) * 32 + 8 * g];
                if (t1 < 13) qS0 = v; else qS1 = v;
            }
        }
        // stage 32x128 x-chunk (rows >= NTOK zeroed)
        for (int idx = tid * 4; idx < 4096; idx += 3328){
            int r = idx >> 7, cc = idx & 127;
            int row = tok0 + r;
            if (isb){
                uint2 a = make_uint2(0u, 0u);
                if (row < NTOK)
                    a = *(const uint2*)((const u16*)xP + xbase + (long)row * 128 + cc);
                *(uint2*)&xs_hi[r * 136 + cc] = a;
            } else {
                u32 h01, h23, l01, l23;
                if (row < NTOK){
                    float4 f = *(const float4*)((const float*)xP + xbase + (long)row * 128 + cc);
                    u16 h0=f2bf(f.x), h1=f2bf(f.y), h2=f2bf(f.z), h3=f2bf(f.w);
                    h01 = h0 | ((u32)h1 << 16); h23 = h2 | ((u32)h3 << 16);
                    l01 = (u32)f2bf(f.x - bf2f(h0)) | ((u32)f2bf(f.y - bf2f(h1)) << 16);
                    l23 = (u32)f2bf(f.z - bf2f(h2)) | ((u32)f2bf(f.w - bf2f(h3)) << 16);
                } else { h01 = h23 = l01 = l23 = 0; }
                *(uint2*)&xs_hi[r * 136 + cc] = make_uint2(h01, h23);
                *(uint2*)&xs_lo[r * 136 + cc] = make_uint2(l01, l23);
            }
        }
        __syncthreads();
        if (wv < 12){
            f32x4 acc = {0.f, 0.f, 0.f, 0.f};
            #pragma unroll
            for (int ks = 0; ks < 4; ++ks){
                bf16x8 ah = *(const bf16x8*)&xs_hi[(mtw * 16 + c) * 136 + ks * 32 + 8 * g];
                acc = MFMA16(ah, WHr[ks], acc);
                if (!isb){
                    bf16x8 al = *(const bf16x8*)&xs_lo[(mtw * 16 + c) * 136 + ks * 32 + 8 * g];
                    acc = MFMA16(al, WHr[ks], acc);
                    acc = MFMA16(ah, WLr[ks], acc);
                }
            }
            #pragma unroll
            for (int i = 0; i < 4; ++i){
                int trow = mtw * 16 + 4 * g + i;       // row within chunk
                int tok  = tok0 + trow;                // rows >= NTOK hold zeros (NaN-safe)
                if (ntw < 2)
                    smQ[(ch & 1) * 1024 + trow * 32 + ntw * 16 + c] = f2bf(acc[i] * QSCL);
                else if (ntw < 4)
                    Kh[tok * 32 + (ntw - 2) * 16 + c] = f2bf(acc[i]);
                else
                    VT[((ntw - 4) * 16 + c) * 416 + tok] = f2bf(acc[i]);
            }
        }
    }
    __syncthreads();                     // K/V complete; last smQ visible
    {   // final Q grab (chunk 12 -> tasks 24,25)
        const u16* sq = smQ + (12 & 1) * 1024;
        if (wv == 24 % 13){
            bf16x8 v = *(const bf16x8*)&sq[c * 32 + 8 * g];
            qS1 = v;                     // task 24 = slot 1 of wave 11
        }
        if (wv == 25 % 13){
            bf16x8 v = *(const bf16x8*)&sq[(16 + c) * 32 + 8 * g];
            qS1 = v;                     // task 25 = slot 1 of wave 12
        }
    }

    // ---------- phase 2: 2 passes x 13 waves = 26 tasks of 16 q-rows ----------
    u16* pb = uni + wv * 640;            // per-wave 16x32 P tile, stride 40 (u16)
    const u16* bHh = biasH + (long)h * BTH;
    const long mbase = (long)wdx * NN2;

    for (int pass = 0; pass < 2; ++pass){
        const int t  = wv + 13 * pass;
        const int q0 = t * 16;
        bf16x8 qA = pass ? qS1 : qS0;
        const u16* bp = bHh + (long)(q0 + c) * BTK;
        f32x4 o0 = {0.f,0.f,0.f,0.f}, o1 = {0.f,0.f,0.f,0.f};
        float rs = 0.f;
        uint2 bre = *(const uint2*)(bp + 4 * g);
        uint2 bro = *(const uint2*)(bp + 16 + 4 * g);
        for (int k2 = 0; k2 < 13; ++k2){
            const int kk = k2 * 32;
            uint2 ue = bre, uo = bro;
            if (k2 < 12){
                bre = *(const uint2*)(bp + kk + 32 + 4 * g);
                bro = *(const uint2*)(bp + kk + 48 + 4 * g);
            }
            f32x4 cE = h4tof(ue), cO = h4tof(uo);
            if (fm){
                int q_ = q0 + c; if (q_ >= NTOK) q_ = NTOK - 1;
                #pragma unroll
                for (int i = 0; i < 4; ++i){
                    int ke = kk + 4 * g + i;      int kce = ke < NTOK ? ke : NTOK - 1;
                    int ko = kk + 16 + 4 * g + i; int kco = ko < NTOK ? ko : NTOK - 1;
                    cE[i] += ldf(maskP, isb, mbase + (long)q_ * NTOK + kce) * LOG2E;
                    cO[i] += ldf(maskP, isb, mbase + (long)q_ * NTOK + kco) * LOG2E;
                }
            }
            bf16x8 kbE = *(const bf16x8*)&Kh[(kk + c) * 32 + 8 * g];
            bf16x8 kbO = *(const bf16x8*)&Kh[(kk + 16 + c) * 32 + 8 * g];
            f32x4 sE = MFMA16(kbE, qA, cE);
            f32x4 sO = MFMA16(kbO, qA, cO);
            float pE[4], pO[4];
            #pragma unroll
            for (int i = 0; i < 4; ++i){ pE[i] = exp2f(sE[i]); pO[i] = exp2f(sO[i]); }
            rs += ((pE[0]+pE[1]) + (pE[2]+pE[3])) + ((pO[0]+pO[1]) + (pO[2]+pO[3]));
            *(uint2*)&pb[c * 40 + 4 * g]      = make_uint2(pk2(pE[0],pE[1]), pk2(pE[2],pE[3]));
            *(uint2*)&pb[c * 40 + 16 + 4 * g] = make_uint2(pk2(pO[0],pO[1]), pk2(pO[2],pO[3]));
            bf16x8 pa = *(const bf16x8*)&pb[c * 40 + 8 * g];
            bf16x8 v0 = *(const bf16x8*)&VT[c * 416 + kk + 8 * g];
            bf16x8 v1 = *(const bf16x8*)&VT[(c + 16) * 416 + kk + 8 * g];
            o0 = MFMA16(pa, v0, o0);
            o1 = MFMA16(pa, v1, o1);
        }
        rs += __shfl_xor(rs, 16, 64);
        rs += __shfl_xor(rs, 32, 64);
        #pragma unroll
        for (int i = 0; i < 4; ++i){
            float S = __shfl(rs, 4 * g + i, 64);   // lane 4g+i holds row q0+4g+i's sum
            int tok = q0 + 4 * g + i;
            if (tok < NTOK){
                float iv = 1.f / S;
                stf(outP, isb, xbase + (long)tok * 128 + h * 32 + c,      o0[i] * iv);
                stf(outP, isb, xbase + (long)tok * 128 + h * 32 + 16 + c, o1[i] * iv);
            }
        }
    }
}

// ---------- kernel E: out = O @ proj_w^T + proj_b (MFMA, in-place on d_out) ----------
__global__ __launch_bounds__(512) void proj_mfma_kernel(
        const void* wP, const void* bP, const int* __restrict__ flags,
        void* outP){
    __shared__ __align__(16) u16 xs_hi[64 * 136];
    __shared__ __align__(16) u16 xs_lo[64 * 136];   // 69632 B -> 2 blocks/CU
    const int tid  = threadIdx.x;
    const int lane = tid & 63;
    const int wv   = tid >> 6;
    const int c    = lane & 15;
    const int g    = lane >> 4;
    const int isb  = flags[0];
    const long m0  = (long)blockIdx.x * 64;

    #pragma unroll
    for (int jj = 0; jj < 4; ++jj){
        int idx = jj * 2048 + tid * 4;
        int r = idx >> 7, cc = idx & 127;
        long gi = (m0 + r) * 128 + cc;
        if (isb){
            uint2 a = *(const uint2*)((const u16*)outP + gi);
            *(uint2*)&xs_hi[r * 136 + cc] = a;
        } else {
            float4 f = *(const float4*)((const float*)outP + gi);
            u16 h0=f2bf(f.x), h1=f2bf(f.y), h2=f2bf(f.z), h3=f2bf(f.w);
            u32 h01 = h0 | ((u32)h1 << 16), h23 = h2 | ((u32)h3 << 16);
            u32 l01 = (u32)f2bf(f.x - bf2f(h0)) | ((u32)f2bf(f.y - bf2f(h1)) << 16);
            u32 l23 = (u32)f2bf(f.z - bf2f(h2)) | ((u32)f2bf(f.w - bf2f(h3)) << 16);
            *(uint2*)&xs_hi[r * 136 + cc] = make_uint2(h01, h23);
            *(uint2*)&xs_lo[r * 136 + cc] = make_uint2(l01, l23);
        }
    }
    __syncthreads();
    const int mt  = wv >> 1;
    const int ntb = (wv & 1) * 4;
    bf16x8 ah[4], al[4];
    #pragma unroll
    for (int ks = 0; ks < 4; ++ks){
        ah[ks] = *(const bf16x8*)&xs_hi[(mt * 16 + c) * 136 + ks * 32 + 8 * g];
        if (!isb)
            al[ks] = *(const bf16x8*)&xs_lo[(mt * 16 + c) * 136 + ks * 32 + 8 * g];
    }
    #pragma unroll
    for (int j = 0; j < 4; ++j){
        int nt = ntb + j;
        bf16x8 wh[4], wl[4];
        #pragma unroll
        for (int ks = 0; ks < 4; ++ks)
            ld8s(wP, isb, (long)(nt * 16 + c) * 128 + ks * 32 + 8 * g, &wh[ks], &wl[ks]);
        f32x4 acc = {0.f,0.f,0.f,0.f};
        #pragma unroll
        for (int ks = 0; ks < 4; ++ks){
            acc = MFMA16(ah[ks], wh[ks], acc);
            if (!isb){
                acc = MFMA16(al[ks], wh[ks], acc);
                acc = MFMA16(ah[ks], wl[ks], acc);
            }
        }
        float bias = ldf(bP, isb, nt * 16 + c);
        #pragma unroll
        for (int i = 0; i < 4; ++i){
            long row = m0 + mt * 16 + 4 * g + i;
            stf(outP, isb, row * 128 + nt * 16 + c, acc[i] + bias);
        }
    }
}

// ---------- launch ----------
extern "C" void kernel_launch(void* const* d_in, const int* in_sizes, int n_in,
                              void* d_out, int out_size, void* d_ws, size_t ws_size,
                              hipStream_t stream){
    const void* x      = d_in[0];
    const void* mask   = d_in[1];
    const void* qkv_w  = d_in[2];
    const void* proj_w = d_in[3];
    const void* proj_b = d_in[4];
    const void* btab   = d_in[5];
    const int*  relidx = (const int*)d_in[6];

    int* flags = (int*)d_ws;
    u16* biasH = (u16*)((char*)d_ws + 256);   // 4*416*416 fp16 = 1.38 MB

    prep_kernel<<<dim3(1), dim3(256), 0, stream>>>((const u16*)x, flags);
    int nhalf = in_sizes[1] / 2;
    mask_scan_kernel<<<dim3(2048), dim3(256), 0, stream>>>(
        (const u32*)mask, nhalf, flags, flags);
    bias_expand_kernel<<<dim3((int)((BTH + 255) / 256)), dim3(256), 0, stream>>>(
        relidx, btab, flags, biasH);
    attn_mfma_kernel<<<dim3(4, 512), dim3(832), 0, stream>>>(
        x, qkv_w, mask, biasH, flags, d_out);
    proj_mfma_kernel<<<dim3(3136), dim3(512), 0, stream>>>(
        proj_w, proj_b, flags, d_out);
}